// Round 1
// baseline (7403.915 us; speedup 1.0000x reference)
//
#include <hip/hip_runtime.h>
#include <math.h>

#define BATCH 32
#define NTOK 20
#define DMODEL 768
#define NH 12
#define DHEAD 64
#define MKEYS 16384
#define KTOP 32

__device__ __forceinline__ float gelu_f(float v) {
  float u = 0.7978845608028654f * (v + 0.044715f * v * v * v);
  return 0.5f * v * (1.0f + tanhf(u));
}

// ---------------------------------------------------------------------------
// seq[b][ct][d] = x[b] @ W_lin[:, ct*768+d] + b_lin  (clip tokens 0..9)
// grid (10, 6, 4) block 128: ct = bx, d = by*128+tid, b-group = bz*8
// ---------------------------------------------------------------------------
__global__ __launch_bounds__(128) void lin_kernel(const float* __restrict__ x,
                                                  const float* __restrict__ W,
                                                  const float* __restrict__ bias,
                                                  float* __restrict__ seq) {
  __shared__ float xs[8 * 512];
  int tid = threadIdx.x;
  int bg = blockIdx.z * 8;
  for (int idx = tid; idx < 8 * 512; idx += 128) xs[idx] = x[bg * 512 + idx];
  __syncthreads();
  int ct = blockIdx.x;
  int d = blockIdx.y * 128 + tid;
  int col = ct * DMODEL + d;
  float acc[8] = {};
  for (int k = 0; k < 512; ++k) {
    float w = W[(size_t)k * 7680 + col];
#pragma unroll
    for (int b = 0; b < 8; ++b) acc[b] += xs[b * 512 + k] * w;
  }
  float bb = bias[col];
#pragma unroll
  for (int b = 0; b < 8; ++b)
    seq[(size_t)((bg + b) * NTOK + ct) * DMODEL + d] = acc[b] + bb;
}

// seq[b][10+p][d] = prefix_const[p][d]
__global__ void prefix_kernel(const float* __restrict__ pc, float* __restrict__ seq) {
  int t = blockIdx.x * 256 + threadIdx.x;
  if (t < BATCH * 10 * DMODEL) {
    int b = t / (10 * DMODEL), r = t % (10 * DMODEL);
    seq[(size_t)(b * NTOK + 10) * DMODEL + r] = pc[r];
  }
}

// ---------------------------------------------------------------------------
// LayerNorm: one block per row (640 rows), 256 threads, 3 elems/thread
// ---------------------------------------------------------------------------
__global__ __launch_bounds__(256) void ln_kernel(const float* __restrict__ X,
                                                 const float* __restrict__ g,
                                                 const float* __restrict__ bt,
                                                 float* __restrict__ Y) {
  int row = blockIdx.x;
  const float* xr = X + (size_t)row * DMODEL;
  int tid = threadIdx.x;
  float e0 = xr[tid], e1 = xr[tid + 256], e2 = xr[tid + 512];
  float s1 = e0 + e1 + e2;
  float s2 = e0 * e0 + e1 * e1 + e2 * e2;
#pragma unroll
  for (int off = 32; off; off >>= 1) {
    s1 += __shfl_xor(s1, off);
    s2 += __shfl_xor(s2, off);
  }
  __shared__ float r1[4], r2[4];
  int w = tid >> 6;
  if ((tid & 63) == 0) { r1[w] = s1; r2[w] = s2; }
  __syncthreads();
  s1 = r1[0] + r1[1] + r1[2] + r1[3];
  s2 = r2[0] + r2[1] + r2[2] + r2[3];
  float mean = s1 * (1.0f / DMODEL);
  float var = s2 * (1.0f / DMODEL) - mean * mean;
  float rstd = rsqrtf(var + 1e-5f);
  float* yr = Y + (size_t)row * DMODEL;
  yr[tid]       = (e0 - mean) * rstd * g[tid]       + bt[tid];
  yr[tid + 256] = (e1 - mean) * rstd * g[tid + 256] + bt[tid + 256];
  yr[tid + 512] = (e2 - mean) * rstd * g[tid + 512] + bt[tid + 512];
}

// Final LN over prefix tokens only -> d_out (fp32), 320 rows
__global__ __launch_bounds__(256) void lnf_kernel(const float* __restrict__ X,
                                                  const float* __restrict__ g,
                                                  const float* __restrict__ bt,
                                                  float* __restrict__ out) {
  int row = blockIdx.x;  // 0..319
  int b = row / 10, p = row % 10;
  const float* xr = X + (size_t)(b * NTOK + 10 + p) * DMODEL;
  int tid = threadIdx.x;
  float e0 = xr[tid], e1 = xr[tid + 256], e2 = xr[tid + 512];
  float s1 = e0 + e1 + e2;
  float s2 = e0 * e0 + e1 * e1 + e2 * e2;
#pragma unroll
  for (int off = 32; off; off >>= 1) {
    s1 += __shfl_xor(s1, off);
    s2 += __shfl_xor(s2, off);
  }
  __shared__ float r1[4], r2[4];
  int w = tid >> 6;
  if ((tid & 63) == 0) { r1[w] = s1; r2[w] = s2; }
  __syncthreads();
  s1 = r1[0] + r1[1] + r1[2] + r1[3];
  s2 = r2[0] + r2[1] + r2[2] + r2[3];
  float mean = s1 * (1.0f / DMODEL);
  float var = s2 * (1.0f / DMODEL) - mean * mean;
  float rstd = rsqrtf(var + 1e-5f);
  float* yr = out + (size_t)row * DMODEL;
  yr[tid]       = (e0 - mean) * rstd * g[tid]       + bt[tid];
  yr[tid + 256] = (e1 - mean) * rstd * g[tid + 256] + bt[tid + 256];
  yr[tid + 512] = (e2 - mean) * rstd * g[tid + 512] + bt[tid + 512];
}

// ---------------------------------------------------------------------------
// fp32 GEMM: C[M,N] = A[M,K] @ W[K,N]  (+R residual, optional gelu)
// 64x64 tile, 256 threads, 4x4 per thread, K-chunk 16.
// flags: bit0 = residual add, bit1 = gelu
// ---------------------------------------------------------------------------
__global__ __launch_bounds__(256) void gemm_kernel(const float* __restrict__ A,
                                                   const float* __restrict__ W,
                                                   const float* __restrict__ R,
                                                   float* __restrict__ C,
                                                   int M, int K, int N, int flags) {
  __shared__ float As[16][68];
  __shared__ float Bs[16][68];
  int tid = threadIdx.x;
  int n0 = blockIdx.x * 64, m0 = blockIdx.y * 64;
  int mi = tid >> 4, ni = tid & 15;
  int am = tid >> 2, ak = (tid & 3) * 4;   // A staging: 64 rows x 16 k
  int wk = tid >> 4, wn = (tid & 15) * 4;  // W staging: 16 k x 64 n
  float acc[4][4] = {};
  for (int k0 = 0; k0 < K; k0 += 16) {
    __syncthreads();
    float4 a4 = *(const float4*)&A[(size_t)(m0 + am) * K + k0 + ak];
    As[ak + 0][am] = a4.x;
    As[ak + 1][am] = a4.y;
    As[ak + 2][am] = a4.z;
    As[ak + 3][am] = a4.w;
    *(float4*)&Bs[wk][wn] = *(const float4*)&W[(size_t)(k0 + wk) * N + n0 + wn];
    __syncthreads();
#pragma unroll
    for (int kk = 0; kk < 16; ++kk) {
      float4 av = *(const float4*)&As[kk][mi * 4];
      float4 bv = *(const float4*)&Bs[kk][ni * 4];
      acc[0][0] += av.x * bv.x; acc[0][1] += av.x * bv.y; acc[0][2] += av.x * bv.z; acc[0][3] += av.x * bv.w;
      acc[1][0] += av.y * bv.x; acc[1][1] += av.y * bv.y; acc[1][2] += av.y * bv.z; acc[1][3] += av.y * bv.w;
      acc[2][0] += av.z * bv.x; acc[2][1] += av.z * bv.y; acc[2][2] += av.z * bv.z; acc[2][3] += av.z * bv.w;
      acc[3][0] += av.w * bv.x; acc[3][1] += av.w * bv.y; acc[3][2] += av.w * bv.z; acc[3][3] += av.w * bv.w;
    }
  }
#pragma unroll
  for (int i = 0; i < 4; ++i) {
    int row = m0 + mi * 4 + i;
    int colb = n0 + ni * 4;
    float4 c = {acc[i][0], acc[i][1], acc[i][2], acc[i][3]};
    if (flags & 2) { c.x = gelu_f(c.x); c.y = gelu_f(c.y); c.z = gelu_f(c.z); c.w = gelu_f(c.w); }
    if (flags & 1) {
      float4 r = *(const float4*)&R[(size_t)row * N + colb];
      c.x += r.x; c.y += r.y; c.z += r.z; c.w += r.w;
    }
    *(float4*)&C[(size_t)row * N + colb] = c;
  }
}

// ---------------------------------------------------------------------------
// Top-K=32 over 16384 memory keys, per (b,h,query). One block per (b,h),
// 320 threads = 5 waves; wave w owns queries 4w..4w+3; lane owns keys
// lane + 64*kj within a 512-key tile. Online top-32 via ballot + serialized
// insert into an LDS list with running min threshold.
// ---------------------------------------------------------------------------
__global__ __launch_bounds__(320) void topk_kernel(const float* __restrict__ qkv,
                                                   const float* __restrict__ mem_k,
                                                   float* __restrict__ tkS,
                                                   int* __restrict__ tkI) {
  int blk = blockIdx.x;
  int b = blk / NH, h = blk % NH;
  __shared__ float qs[NTOK * DHEAD];
  __shared__ float ks[16 * 513];   // [d within chunk][key], pad 513 vs 512
  __shared__ float listS[NTOK * KTOP];
  __shared__ int   listI[NTOK * KTOP];
  __shared__ float thrS[NTOK];
  int tid = threadIdx.x;
  for (int idx = tid; idx < NTOK * DHEAD; idx += 320) {
    int i = idx >> 6, d = idx & 63;
    qs[idx] = qkv[(size_t)(b * NTOK + i) * 2304 + h * DHEAD + d];
  }
  for (int idx = tid; idx < NTOK * KTOP; idx += 320) { listS[idx] = -1e30f; listI[idx] = 0; }
  if (tid < NTOK) thrS[tid] = -1e30f;
  __syncthreads();
  int wave = tid >> 6, lane = tid & 63;
  int qbase = wave * 4;

  for (int tile = 0; tile < MKEYS / 512; ++tile) {
    int key0 = tile * 512;
    float acc[4][8] = {};
    for (int dc = 0; dc < 4; ++dc) {
      __syncthreads();
      for (int idx = tid; idx < 2048; idx += 320) {
        int key = idx >> 2, dj = (idx & 3) * 4;
        float4 kv = *(const float4*)&mem_k[((size_t)b * MKEYS + key0 + key) * DHEAD + dc * 16 + dj];
        ks[(dj + 0) * 513 + key] = kv.x;
        ks[(dj + 1) * 513 + key] = kv.y;
        ks[(dj + 2) * 513 + key] = kv.z;
        ks[(dj + 3) * 513 + key] = kv.w;
      }
      __syncthreads();
#pragma unroll
      for (int d = 0; d < 16; ++d) {
        float q0 = qs[(qbase + 0) * DHEAD + dc * 16 + d];
        float q1 = qs[(qbase + 1) * DHEAD + dc * 16 + d];
        float q2 = qs[(qbase + 2) * DHEAD + dc * 16 + d];
        float q3 = qs[(qbase + 3) * DHEAD + dc * 16 + d];
#pragma unroll
        for (int kj = 0; kj < 8; ++kj) {
          float kv = ks[d * 513 + lane + 64 * kj];
          acc[0][kj] += q0 * kv;
          acc[1][kj] += q1 * kv;
          acc[2][kj] += q2 * kv;
          acc[3][kj] += q3 * kv;
        }
      }
    }
    // top-k update (wave-local; each query owned by exactly one wave)
#pragma unroll
    for (int qi = 0; qi < 4; ++qi) {
      int q = qbase + qi;
#pragma unroll
      for (int kj = 0; kj < 8; ++kj) {
        float s = acc[qi][kj];
        int mykey = key0 + lane + 64 * kj;
        unsigned long long mask = __ballot(s > thrS[q]);
        while (mask) {
          int src = __builtin_ctzll(mask);
          mask &= mask - 1;
          float sv = __shfl(s, src);
          int ki = __shfl(mykey, src);
          if (sv > thrS[q]) {  // re-check against updated threshold (uniform)
            int sl = lane & 31;
            float ls = listS[q * KTOP + sl];
            int li = sl;
#pragma unroll
            for (int off = 16; off; off >>= 1) {
              float os = __shfl_xor(ls, off);
              int oi = __shfl_xor(li, off);
              if (os < ls) { ls = os; li = oi; }
            }
            if (lane == 0) { listS[q * KTOP + li] = sv; listI[q * KTOP + li] = ki; }
            float ns = ((lane & 31) == li) ? sv : listS[q * KTOP + (lane & 31)];
#pragma unroll
            for (int off = 16; off; off >>= 1) ns = fminf(ns, __shfl_xor(ns, off));
            if (lane == 0) thrS[q] = ns;
          }
        }
      }
    }
  }
  __syncthreads();
  for (int idx = tid; idx < NTOK * KTOP; idx += 320) {
    tkS[(size_t)blk * NTOK * KTOP + idx] = listS[idx];
    tkI[(size_t)blk * NTOK * KTOP + idx] = listI[idx];
  }
}

// ---------------------------------------------------------------------------
// Attention (local causal, n=20; + optional top-K memory branch).
// One block per (b,h), 320 threads.
// ---------------------------------------------------------------------------
__global__ __launch_bounds__(320) void attn_kernel(const float* __restrict__ qkv,
                                                   const float* __restrict__ tkS,
                                                   const int* __restrict__ tkI,
                                                   const float* __restrict__ mem_v,
                                                   float* __restrict__ obuf, int use_mem) {
  int blk = blockIdx.x;
  int b = blk / NH, h = blk % NH;
  __shared__ float qs[NTOK * 68], ksh[NTOK * 68], vs[NTOK * 68];
  __shared__ float lg[NTOK * 64];
  int tid = threadIdx.x;
  for (int idx = tid; idx < NTOK * DHEAD; idx += 320) {
    int i = idx >> 6, d = idx & 63;
    const float* base = qkv + (size_t)(b * NTOK + i) * 2304 + h * DHEAD + d;
    qs[i * 68 + d] = base[0];
    ksh[i * 68 + d] = base[DMODEL];
    vs[i * 68 + d] = base[2 * DMODEL];
  }
  __syncthreads();
  for (int p = tid; p < NTOK * NTOK; p += 320) {
    int i = p / NTOK, j = p % NTOK;
    float s = 0.0f;
#pragma unroll
    for (int d = 0; d < DHEAD; ++d) s += qs[i * 68 + d] * ksh[j * 68 + d];
    lg[i * 64 + j] = (j <= i) ? s * 0.125f : -1e9f;
  }
  if (use_mem) {
    for (int p = tid; p < NTOK * KTOP; p += 320) {
      int i = p >> 5, kk = p & 31;
      lg[i * 64 + NTOK + kk] = tkS[(size_t)blk * NTOK * KTOP + i * KTOP + kk] * 0.125f;
    }
  }
  __syncthreads();
  int i = tid >> 4, dq = tid & 15;
  int nl = use_mem ? (NTOK + KTOP) : NTOK;
  float m = -1e30f;
  for (int j = 0; j < nl; ++j) m = fmaxf(m, lg[i * 64 + j]);
  float sum = 0.0f, a0 = 0, a1 = 0, a2 = 0, a3 = 0;
  for (int j = 0; j < NTOK; ++j) {
    float wj = __expf(lg[i * 64 + j] - m);
    sum += wj;
    const float* vr = &vs[j * 68 + dq * 4];
    a0 += wj * vr[0]; a1 += wj * vr[1]; a2 += wj * vr[2]; a3 += wj * vr[3];
  }
  if (use_mem) {
    int base = blk * NTOK * KTOP + i * KTOP;
    for (int kk = 0; kk < KTOP; ++kk) {
      float wj = __expf(lg[i * 64 + NTOK + kk] - m);
      sum += wj;
      int ki = tkI[base + kk];
      float4 mv = *(const float4*)&mem_v[((size_t)b * MKEYS + ki) * DHEAD + dq * 4];
      a0 += wj * mv.x; a1 += wj * mv.y; a2 += wj * mv.z; a3 += wj * mv.w;
    }
  }
  float inv = 1.0f / sum;
  float4 o = {a0 * inv, a1 * inv, a2 * inv, a3 * inv};
  *(float4*)&obuf[(size_t)(b * NTOK + i) * DMODEL + h * DHEAD + dq * 4] = o;
}

// ---------------------------------------------------------------------------
extern "C" void kernel_launch(void* const* d_in, const int* in_sizes, int n_in,
                              void* d_out, int out_size, void* d_ws, size_t ws_size,
                              hipStream_t stream) {
  const float* x       = (const float*)d_in[0];
  const float* W_lin   = (const float*)d_in[1];
  const float* b_lin   = (const float*)d_in[2];
  const float* prefixc = (const float*)d_in[3];
  const float* ln1_g   = (const float*)d_in[4];
  const float* ln1_b   = (const float*)d_in[5];
  const float* ln2_g   = (const float*)d_in[6];
  const float* ln2_b   = (const float*)d_in[7];
  const float* Wqkv    = (const float*)d_in[8];
  const float* Wo      = (const float*)d_in[9];
  const float* Wff1    = (const float*)d_in[10];
  const float* Wff2    = (const float*)d_in[11];
  const float* lnf_g   = (const float*)d_in[12];
  const float* lnf_b   = (const float*)d_in[13];
  const float* mem_k   = (const float*)d_in[14];
  const float* mem_v   = (const float*)d_in[15];

  float* ws   = (float*)d_ws;
  float* seq  = ws;                 // 640*768
  float* ybuf = ws + 491520;        // 640*768
  float* qkvb = ws + 983040;        // 640*2304
  float* obuf = ws + 2457600;       // 640*768
  float* ffb  = ws + 2949120;       // 640*3072
  float* tkS  = ws + 4915200;       // 384*640
  int*   tkI  = (int*)(ws + 5160960);

  lin_kernel<<<dim3(10, 6, 4), 128, 0, stream>>>(x, W_lin, b_lin, seq);
  prefix_kernel<<<960, 256, 0, stream>>>(prefixc, seq);

  for (int l = 0; l < 8; ++l) {
    ln_kernel<<<640, 256, 0, stream>>>(seq, ln1_g + l * 768, ln1_b + l * 768, ybuf);
    gemm_kernel<<<dim3(36, 10), 256, 0, stream>>>(ybuf, Wqkv + (size_t)l * 768 * 2304,
                                                  nullptr, qkvb, 640, 768, 2304, 0);
    if (l == 4)
      topk_kernel<<<384, 320, 0, stream>>>(qkvb, mem_k, tkS, tkI);
    attn_kernel<<<384, 320, 0, stream>>>(qkvb, tkS, tkI, mem_v, obuf, (l == 4) ? 1 : 0);
    gemm_kernel<<<dim3(12, 10), 256, 0, stream>>>(obuf, Wo + (size_t)l * 768 * 768,
                                                  seq, seq, 640, 768, 768, 1);
    ln_kernel<<<640, 256, 0, stream>>>(seq, ln2_g + l * 768, ln2_b + l * 768, ybuf);
    gemm_kernel<<<dim3(48, 10), 256, 0, stream>>>(ybuf, Wff1 + (size_t)l * 768 * 3072,
                                                  nullptr, ffb, 640, 768, 3072, 2);
    gemm_kernel<<<dim3(12, 10), 256, 0, stream>>>(ffb, Wff2 + (size_t)l * 3072 * 768,
                                                  seq, seq, 640, 3072, 768, 1);
  }
  lnf_kernel<<<320, 256, 0, stream>>>(seq, lnf_g, lnf_b, (float*)d_out);
}

// Round 2
// 4876.799 us; speedup vs baseline: 1.5182x; 1.5182x over previous
//
#include <hip/hip_runtime.h>
#include <math.h>

#define BATCH 32
#define NTOK 20
#define DMODEL 768
#define NH 12
#define DHEAD 64
#define MKEYS 16384
#define KTOP 32

__device__ __forceinline__ float gelu_f(float v) {
  float u = 0.7978845608028654f * (v + 0.044715f * v * v * v);
  return 0.5f * v * (1.0f + tanhf(u));
}

// order-preserving float->u32 transform (monotonic), and inverse
__device__ __forceinline__ unsigned packf(float s) {
  unsigned u = __float_as_uint(s);
  return (u & 0x80000000u) ? ~u : (u | 0x80000000u);
}
__device__ __forceinline__ float unpackf(unsigned k) {
  unsigned u = (k & 0x80000000u) ? (k & 0x7FFFFFFFu) : ~k;
  return __uint_as_float(u);
}

// ---------------------------------------------------------------------------
// seq[b][ct][d] = x[b] @ W_lin[:, ct*768+d] + b_lin  (clip tokens 0..9)
// ---------------------------------------------------------------------------
__global__ __launch_bounds__(128) void lin_kernel(const float* __restrict__ x,
                                                  const float* __restrict__ W,
                                                  const float* __restrict__ bias,
                                                  float* __restrict__ seq) {
  __shared__ float xs[8 * 512];
  int tid = threadIdx.x;
  int bg = blockIdx.z * 8;
  for (int idx = tid; idx < 8 * 512; idx += 128) xs[idx] = x[bg * 512 + idx];
  __syncthreads();
  int ct = blockIdx.x;
  int d = blockIdx.y * 128 + tid;
  int col = ct * DMODEL + d;
  float acc[8] = {};
  for (int k = 0; k < 512; ++k) {
    float w = W[(size_t)k * 7680 + col];
#pragma unroll
    for (int b = 0; b < 8; ++b) acc[b] += xs[b * 512 + k] * w;
  }
  float bb = bias[col];
#pragma unroll
  for (int b = 0; b < 8; ++b)
    seq[(size_t)((bg + b) * NTOK + ct) * DMODEL + d] = acc[b] + bb;
}

__global__ void prefix_kernel(const float* __restrict__ pc, float* __restrict__ seq) {
  int t = blockIdx.x * 256 + threadIdx.x;
  if (t < BATCH * 10 * DMODEL) {
    int b = t / (10 * DMODEL), r = t % (10 * DMODEL);
    seq[(size_t)(b * NTOK + 10) * DMODEL + r] = pc[r];
  }
}

// ---------------------------------------------------------------------------
// LayerNorm: one block per row (640 rows)
// ---------------------------------------------------------------------------
__global__ __launch_bounds__(256) void ln_kernel(const float* __restrict__ X,
                                                 const float* __restrict__ g,
                                                 const float* __restrict__ bt,
                                                 float* __restrict__ Y) {
  int row = blockIdx.x;
  const float* xr = X + (size_t)row * DMODEL;
  int tid = threadIdx.x;
  float e0 = xr[tid], e1 = xr[tid + 256], e2 = xr[tid + 512];
  float s1 = e0 + e1 + e2;
  float s2 = e0 * e0 + e1 * e1 + e2 * e2;
#pragma unroll
  for (int off = 32; off; off >>= 1) {
    s1 += __shfl_xor(s1, off);
    s2 += __shfl_xor(s2, off);
  }
  __shared__ float r1[4], r2[4];
  int w = tid >> 6;
  if ((tid & 63) == 0) { r1[w] = s1; r2[w] = s2; }
  __syncthreads();
  s1 = r1[0] + r1[1] + r1[2] + r1[3];
  s2 = r2[0] + r2[1] + r2[2] + r2[3];
  float mean = s1 * (1.0f / DMODEL);
  float var = s2 * (1.0f / DMODEL) - mean * mean;
  float rstd = rsqrtf(var + 1e-5f);
  float* yr = Y + (size_t)row * DMODEL;
  yr[tid]       = (e0 - mean) * rstd * g[tid]       + bt[tid];
  yr[tid + 256] = (e1 - mean) * rstd * g[tid + 256] + bt[tid + 256];
  yr[tid + 512] = (e2 - mean) * rstd * g[tid + 512] + bt[tid + 512];
}

__global__ __launch_bounds__(256) void lnf_kernel(const float* __restrict__ X,
                                                  const float* __restrict__ g,
                                                  const float* __restrict__ bt,
                                                  float* __restrict__ out) {
  int row = blockIdx.x;  // 0..319
  int b = row / 10, p = row % 10;
  const float* xr = X + (size_t)(b * NTOK + 10 + p) * DMODEL;
  int tid = threadIdx.x;
  float e0 = xr[tid], e1 = xr[tid + 256], e2 = xr[tid + 512];
  float s1 = e0 + e1 + e2;
  float s2 = e0 * e0 + e1 * e1 + e2 * e2;
#pragma unroll
  for (int off = 32; off; off >>= 1) {
    s1 += __shfl_xor(s1, off);
    s2 += __shfl_xor(s2, off);
  }
  __shared__ float r1[4], r2[4];
  int w = tid >> 6;
  if ((tid & 63) == 0) { r1[w] = s1; r2[w] = s2; }
  __syncthreads();
  s1 = r1[0] + r1[1] + r1[2] + r1[3];
  s2 = r2[0] + r2[1] + r2[2] + r2[3];
  float mean = s1 * (1.0f / DMODEL);
  float var = s2 * (1.0f / DMODEL) - mean * mean;
  float rstd = rsqrtf(var + 1e-5f);
  float* yr = out + (size_t)row * DMODEL;
  yr[tid]       = (e0 - mean) * rstd * g[tid]       + bt[tid];
  yr[tid + 256] = (e1 - mean) * rstd * g[tid + 256] + bt[tid + 256];
  yr[tid + 512] = (e2 - mean) * rstd * g[tid + 512] + bt[tid + 512];
}

// ---------------------------------------------------------------------------
// fp32 GEMM: C[M,N] = A[M,K] @ W[K,N]  (+R residual, optional gelu)
// ---------------------------------------------------------------------------
__global__ __launch_bounds__(256) void gemm_kernel(const float* __restrict__ A,
                                                   const float* __restrict__ W,
                                                   const float* __restrict__ R,
                                                   float* __restrict__ C,
                                                   int M, int K, int N, int flags) {
  __shared__ float As[16][68];
  __shared__ float Bs[16][68];
  int tid = threadIdx.x;
  int n0 = blockIdx.x * 64, m0 = blockIdx.y * 64;
  int mi = tid >> 4, ni = tid & 15;
  int am = tid >> 2, ak = (tid & 3) * 4;
  int wk = tid >> 4, wn = (tid & 15) * 4;
  float acc[4][4] = {};
  for (int k0 = 0; k0 < K; k0 += 16) {
    __syncthreads();
    float4 a4 = *(const float4*)&A[(size_t)(m0 + am) * K + k0 + ak];
    As[ak + 0][am] = a4.x;
    As[ak + 1][am] = a4.y;
    As[ak + 2][am] = a4.z;
    As[ak + 3][am] = a4.w;
    *(float4*)&Bs[wk][wn] = *(const float4*)&W[(size_t)(k0 + wk) * N + n0 + wn];
    __syncthreads();
#pragma unroll
    for (int kk = 0; kk < 16; ++kk) {
      float4 av = *(const float4*)&As[kk][mi * 4];
      float4 bv = *(const float4*)&Bs[kk][ni * 4];
      acc[0][0] += av.x * bv.x; acc[0][1] += av.x * bv.y; acc[0][2] += av.x * bv.z; acc[0][3] += av.x * bv.w;
      acc[1][0] += av.y * bv.x; acc[1][1] += av.y * bv.y; acc[1][2] += av.y * bv.z; acc[1][3] += av.y * bv.w;
      acc[2][0] += av.z * bv.x; acc[2][1] += av.z * bv.y; acc[2][2] += av.z * bv.z; acc[2][3] += av.z * bv.w;
      acc[3][0] += av.w * bv.x; acc[3][1] += av.w * bv.y; acc[3][2] += av.w * bv.z; acc[3][3] += av.w * bv.w;
    }
  }
#pragma unroll
  for (int i = 0; i < 4; ++i) {
    int row = m0 + mi * 4 + i;
    int colb = n0 + ni * 4;
    float4 c = {acc[i][0], acc[i][1], acc[i][2], acc[i][3]};
    if (flags & 2) { c.x = gelu_f(c.x); c.y = gelu_f(c.y); c.z = gelu_f(c.z); c.w = gelu_f(c.w); }
    if (flags & 1) {
      float4 r = *(const float4*)&R[(size_t)row * N + colb];
      c.x += r.x; c.y += r.y; c.z += r.z; c.w += r.w;
    }
    *(float4*)&C[(size_t)row * N + colb] = c;
  }
}

// ---------------------------------------------------------------------------
// Top-K stage 1: per (h, slice, b) block computes 20 queries x 1024 keys
// scores and extracts per-slice top-32 fully in registers.
// grid (12, 16, 32), block 256 (4 waves, 5 queries each).
// Output: partS[qid][slice*32 + r] = packed score (u32, idx10 in low bits).
// ---------------------------------------------------------------------------
__global__ __launch_bounds__(256) void topk_part(const float* __restrict__ qkv,
                                                 const float* __restrict__ mem_k,
                                                 unsigned* __restrict__ partS) {
  int h = blockIdx.x, slice = blockIdx.y, b = blockIdx.z;
  __shared__ float qs[NTOK * DHEAD];
  __shared__ float ks[16 * 513];
  int tid = threadIdx.x;
  for (int idx = tid; idx < NTOK * DHEAD; idx += 256) {
    int i = idx >> 6, d = idx & 63;
    qs[idx] = qkv[(size_t)(b * NTOK + i) * 2304 + h * DHEAD + d];
  }
  int wave = tid >> 6, lane = tid & 63;
  int qbase = wave * 5;
  float acc[5][16] = {};
#pragma unroll
  for (int half = 0; half < 2; ++half) {
    int kbase = slice * 1024 + half * 512;
    for (int dc = 0; dc < 4; ++dc) {
      __syncthreads();
      for (int idx = tid; idx < 2048; idx += 256) {
        int key = idx >> 2, dj = (idx & 3) * 4;
        float4 kv = *(const float4*)&mem_k[((size_t)b * MKEYS + kbase + key) * DHEAD + dc * 16 + dj];
        ks[(dj + 0) * 513 + key] = kv.x;
        ks[(dj + 1) * 513 + key] = kv.y;
        ks[(dj + 2) * 513 + key] = kv.z;
        ks[(dj + 3) * 513 + key] = kv.w;
      }
      __syncthreads();
#pragma unroll
      for (int d = 0; d < 16; ++d) {
        float q0 = qs[(qbase + 0) * DHEAD + dc * 16 + d];
        float q1 = qs[(qbase + 1) * DHEAD + dc * 16 + d];
        float q2 = qs[(qbase + 2) * DHEAD + dc * 16 + d];
        float q3 = qs[(qbase + 3) * DHEAD + dc * 16 + d];
        float q4 = qs[(qbase + 4) * DHEAD + dc * 16 + d];
#pragma unroll
        for (int kj = 0; kj < 8; ++kj) {
          float kv = ks[d * 513 + lane + 64 * kj];
          acc[0][half * 8 + kj] += q0 * kv;
          acc[1][half * 8 + kj] += q1 * kv;
          acc[2][half * 8 + kj] += q2 * kv;
          acc[3][half * 8 + kj] += q3 * kv;
          acc[4][half * 8 + kj] += q4 * kv;
        }
      }
    }
  }
  // selection: per query, pack+sort 16 candidates in registers, extract 32
  size_t qrow = ((size_t)(b * NH + h) * NTOK + qbase) * 512 + slice * 32;
#pragma unroll
  for (int qi = 0; qi < 5; ++qi) {
    unsigned lv[16];
#pragma unroll
    for (int j = 0; j < 16; ++j) {
      int half = j >> 3, kj = j & 7;
      unsigned idx10 = (unsigned)(half * 512 + kj * 64 + lane);
      lv[j] = (packf(acc[qi][j]) & ~0x3FFu) | idx10;
    }
    // bitonic sort descending
#pragma unroll
    for (int size = 2; size <= 16; size <<= 1) {
#pragma unroll
      for (int stride = size >> 1; stride > 0; stride >>= 1) {
#pragma unroll
        for (int i = 0; i < 16; ++i) {
          int j = i ^ stride;
          if (j > i) {
            bool dirDesc = ((i & size) == 0);
            unsigned x = lv[i], y = lv[j];
            bool sw = dirDesc ? (x < y) : (x > y);
            unsigned nx = sw ? y : x, ny = sw ? x : y;
            lv[i] = nx; lv[j] = ny;
          }
        }
      }
    }
    unsigned keepS = 0;
    for (int r = 0; r < 32; ++r) {
      unsigned bm = lv[0];
#pragma unroll
      for (int off = 32; off; off >>= 1) {
        unsigned o = __shfl_xor(bm, off);
        bm = (o > bm) ? o : bm;
      }
      if (lane == (int)(bm & 63u)) {
#pragma unroll
        for (int t = 0; t < 15; ++t) lv[t] = lv[t + 1];
        lv[15] = 0;
      }
      if (lane == r) keepS = bm;
    }
    if (lane < 32) partS[qrow + (size_t)qi * 512 + lane] = keepS;
  }
}

// ---------------------------------------------------------------------------
// Top-K stage 2: merge 16 slices x 32 candidates -> global top-32 per query.
// One wave per query; 1920 blocks x 256 threads.
// ---------------------------------------------------------------------------
__global__ __launch_bounds__(256) void topk_merge(const unsigned* __restrict__ partS,
                                                  float* __restrict__ tkS,
                                                  int* __restrict__ tkI) {
  int qid = blockIdx.x * 4 + (threadIdx.x >> 6);
  int lane = threadIdx.x & 63;
  const unsigned* src = partS + (size_t)qid * 512;
  unsigned v[8], kk[8];
#pragma unroll
  for (int c = 0; c < 8; ++c) {
    int pos = lane + 64 * c;
    unsigned s = src[pos];
    v[c] = s;
    kk[c] = (unsigned)((pos >> 5) * 1024) + (s & 0x3FFu);
  }
  // bitonic sort (pairs) descending by v
#pragma unroll
  for (int size = 2; size <= 8; size <<= 1) {
#pragma unroll
    for (int stride = size >> 1; stride > 0; stride >>= 1) {
#pragma unroll
      for (int i = 0; i < 8; ++i) {
        int j = i ^ stride;
        if (j > i) {
          bool dirDesc = ((i & size) == 0);
          bool sw = dirDesc ? (v[i] < v[j]) : (v[i] > v[j]);
          unsigned tv = v[i], tk = kk[i];
          v[i] = sw ? v[j] : v[i];   kk[i] = sw ? kk[j] : kk[i];
          v[j] = sw ? tv : v[j];     kk[j] = sw ? tk : kk[j];
        }
      }
    }
  }
  unsigned keepS = 0, keepK = 0;
  for (int r = 0; r < 32; ++r) {
    unsigned bm = v[0];
#pragma unroll
    for (int off = 32; off; off >>= 1) {
      unsigned o = __shfl_xor(bm, off);
      bm = (o > bm) ? o : bm;
    }
    unsigned long long mb = __ballot(v[0] == bm);
    int wl = __builtin_ctzll(mb);
    unsigned wkey = __shfl(kk[0], wl);
    if (lane == wl) {
#pragma unroll
      for (int t = 0; t < 7; ++t) { v[t] = v[t + 1]; kk[t] = kk[t + 1]; }
      v[7] = 0; kk[7] = 0;
    }
    if (lane == r) { keepS = bm; keepK = wkey; }
  }
  if (lane < 32) {
    tkS[(size_t)qid * 32 + lane] = unpackf(keepS);
    tkI[(size_t)qid * 32 + lane] = (int)keepK;
  }
}

// ---------------------------------------------------------------------------
// Attention (local causal, n=20; + optional top-K memory branch).
// ---------------------------------------------------------------------------
__global__ __launch_bounds__(320) void attn_kernel(const float* __restrict__ qkv,
                                                   const float* __restrict__ tkS,
                                                   const int* __restrict__ tkI,
                                                   const float* __restrict__ mem_v,
                                                   float* __restrict__ obuf, int use_mem) {
  int blk = blockIdx.x;
  int b = blk / NH, h = blk % NH;
  __shared__ float qs[NTOK * 68], ksh[NTOK * 68], vs[NTOK * 68];
  __shared__ float lg[NTOK * 64];
  int tid = threadIdx.x;
  for (int idx = tid; idx < NTOK * DHEAD; idx += 320) {
    int i = idx >> 6, d = idx & 63;
    const float* base = qkv + (size_t)(b * NTOK + i) * 2304 + h * DHEAD + d;
    qs[i * 68 + d] = base[0];
    ksh[i * 68 + d] = base[DMODEL];
    vs[i * 68 + d] = base[2 * DMODEL];
  }
  __syncthreads();
  for (int p = tid; p < NTOK * NTOK; p += 320) {
    int i = p / NTOK, j = p % NTOK;
    float s = 0.0f;
#pragma unroll
    for (int d = 0; d < DHEAD; ++d) s += qs[i * 68 + d] * ksh[j * 68 + d];
    lg[i * 64 + j] = (j <= i) ? s * 0.125f : -1e9f;
  }
  if (use_mem) {
    for (int p = tid; p < NTOK * KTOP; p += 320) {
      int i = p >> 5, kk = p & 31;
      lg[i * 64 + NTOK + kk] = tkS[(size_t)blk * NTOK * KTOP + i * KTOP + kk] * 0.125f;
    }
  }
  __syncthreads();
  int i = tid >> 4, dq = tid & 15;
  int nl = use_mem ? (NTOK + KTOP) : NTOK;
  float m = -1e30f;
  for (int j = 0; j < nl; ++j) m = fmaxf(m, lg[i * 64 + j]);
  float sum = 0.0f, a0 = 0, a1 = 0, a2 = 0, a3 = 0;
  for (int j = 0; j < NTOK; ++j) {
    float wj = __expf(lg[i * 64 + j] - m);
    sum += wj;
    const float* vr = &vs[j * 68 + dq * 4];
    a0 += wj * vr[0]; a1 += wj * vr[1]; a2 += wj * vr[2]; a3 += wj * vr[3];
  }
  if (use_mem) {
    int base = blk * NTOK * KTOP + i * KTOP;
    for (int kk = 0; kk < KTOP; ++kk) {
      float wj = __expf(lg[i * 64 + NTOK + kk] - m);
      sum += wj;
      int ki = tkI[base + kk];
      float4 mv = *(const float4*)&mem_v[((size_t)b * MKEYS + ki) * DHEAD + dq * 4];
      a0 += wj * mv.x; a1 += wj * mv.y; a2 += wj * mv.z; a3 += wj * mv.w;
    }
  }
  float inv = 1.0f / sum;
  float4 o = {a0 * inv, a1 * inv, a2 * inv, a3 * inv};
  *(float4*)&obuf[(size_t)(b * NTOK + i) * DMODEL + h * DHEAD + dq * 4] = o;
}

// ---------------------------------------------------------------------------
extern "C" void kernel_launch(void* const* d_in, const int* in_sizes, int n_in,
                              void* d_out, int out_size, void* d_ws, size_t ws_size,
                              hipStream_t stream) {
  const float* x       = (const float*)d_in[0];
  const float* W_lin   = (const float*)d_in[1];
  const float* b_lin   = (const float*)d_in[2];
  const float* prefixc = (const float*)d_in[3];
  const float* ln1_g   = (const float*)d_in[4];
  const float* ln1_b   = (const float*)d_in[5];
  const float* ln2_g   = (const float*)d_in[6];
  const float* ln2_b   = (const float*)d_in[7];
  const float* Wqkv    = (const float*)d_in[8];
  const float* Wo      = (const float*)d_in[9];
  const float* Wff1    = (const float*)d_in[10];
  const float* Wff2    = (const float*)d_in[11];
  const float* lnf_g   = (const float*)d_in[12];
  const float* lnf_b   = (const float*)d_in[13];
  const float* mem_k   = (const float*)d_in[14];
  const float* mem_v   = (const float*)d_in[15];

  float* ws   = (float*)d_ws;
  float* seq  = ws;                       // 640*768
  float* ybuf = ws + 491520;              // 640*768
  float* qkvb = ws + 983040;              // 640*2304
  float* obuf = ws + 2457600;             // 640*768
  float* ffb  = ws + 2949120;             // 640*3072
  float* tkS  = ws + 4915200;             // 384*640
  int*   tkI  = (int*)(ws + 5160960);     // 384*640
  unsigned* partS = (unsigned*)(ws + 5406720);  // 7680*512 u32 = 15.7 MB

  lin_kernel<<<dim3(10, 6, 4), 128, 0, stream>>>(x, W_lin, b_lin, seq);
  prefix_kernel<<<960, 256, 0, stream>>>(prefixc, seq);

  for (int l = 0; l < 8; ++l) {
    ln_kernel<<<640, 256, 0, stream>>>(seq, ln1_g + l * 768, ln1_b + l * 768, ybuf);
    gemm_kernel<<<dim3(36, 10), 256, 0, stream>>>(ybuf, Wqkv + (size_t)l * 768 * 2304,
                                                  nullptr, qkvb, 640, 768, 2304, 0);
    if (l == 4) {
      topk_part<<<dim3(12, 16, 32), 256, 0, stream>>>(qkvb, mem_k, partS);
      topk_merge<<<1920, 256, 0, stream>>>(partS, tkS, tkI);
    }
    attn_kernel<<<384, 320, 0, stream>>>(qkvb, tkS, tkI, mem_v, obuf, (l == 4) ? 1 : 0);
    gemm_kernel<<<dim3(12, 10), 256, 0, stream>>>(obuf, Wo + (size_t)l * 768 * 768,
                                                  seq, seq, 640, 768, 768, 1);
    ln_kernel<<<640, 256, 0, stream>>>(seq, ln2_g + l * 768, ln2_b + l * 768, ybuf);
    gemm_kernel<<<dim3(48, 10), 256, 0, stream>>>(ybuf, Wff1 + (size_t)l * 768 * 3072,
                                                  nullptr, ffb, 640, 768, 3072, 2);
    gemm_kernel<<<dim3(12, 10), 256, 0, stream>>>(ffb, Wff2 + (size_t)l * 3072 * 768,
                                                  seq, seq, 640, 3072, 768, 1);
  }
  lnf_kernel<<<320, 256, 0, stream>>>(seq, lnf_g, lnf_b, (float*)d_out);
}